// Round 11
// baseline (142.861 us; speedup 1.0000x reference)
//
#include <hip/hip_runtime.h>
#include <math.h>

#define NTOK 100
#define EDIM 5
#define NH   4
#define NL   3
#define DD   64
#define BLK  512

// single-instruction transcendentals (1-ulp class; tolerance is 2^-7;
// HW-validated rounds 3-10)
__device__ __forceinline__ float fexp2(float x){ float r; asm("v_exp_f32 %0, %1" : "=v"(r) : "v"(x)); return r; }
__device__ __forceinline__ float frcp (float x){ float r; asm("v_rcp_f32 %0, %1" : "=v"(r) : "v"(x)); return r; }
__device__ __forceinline__ float frsq (float x){ float r; asm("v_rsq_f32 %0, %1" : "=v"(r) : "v"(x)); return r; }

// ---------------------------------------------------------------------------
// SINGLE fused kernel (round 11).  r10 proved the single-launch fixed-cost
// saving is real (~7.7 us: fixed 69.4 vs 77) but its per-thread scalar-dot
// precompute cost ~23 us/block (L2-latency-bound scalar loads).  Round 11
// replaces it with a WAVE-BUTTERFLY precompute (~1 us/block):
//   - 24 matrices (M = (1/8)*log2e * Wq^T Wk ; P = Wv^T Wo_h^T), 3 per wave
//   - lane d loads row d of A and B (coalesced), forms 25 products in regs
//     (all indices compile-time -> registers, not scratch)
//   - 6-step __shfl_xor butterfly reduces the 25 values across 64 lanes
//   - lane 0 writes the 5x5 result into LDS s_MP4
// Everything downstream = r8's best structure: 512 thr, 1 row/thread,
// j-split 2, LDS-broadcast j-loop unroll 8, lean math, (512,4) cap 128.
// ---------------------------------------------------------------------------
__global__ __launch_bounds__(BLK, 4) void encoder_kernel(
    const float* __restrict__ x,
    const float* __restrict__ Wq,
    const float* __restrict__ Wk,
    const float* __restrict__ Wv,
    const float* __restrict__ Wo,
    const float* __restrict__ Wf,
    const float* __restrict__ bfv,
    const float* __restrict__ g1,
    const float* __restrict__ b1,
    const float* __restrict__ g2,
    const float* __restrict__ b2,
    float* __restrict__ out)
{
  const int b = blockIdx.x, t = threadIdx.x;
  const int wvid = t >> 6, lane = t & 63;

  __shared__ float4 s_MP4[480];             // 7680 B: M then P
  __shared__ float4 s_o4[NTOK+2];           // token state [0..3]
  __shared__ float  s_o1[NTOK+2];           // token state [4]
  __shared__ float4 s_w4[2][NH][NTOK+2];    // wp[0..3] per (jgroup,h,i)
  __shared__ float2 s_w2[2][NH][NTOK+2];    // {wp[4], ls}
  __shared__ float  s_cf[152];              // Wf | bf | g1 | b1 | g2 | b2
  __shared__ int    s_cidx[NTOK];
  __shared__ unsigned long long s_bal[2];

  const float* mpf = (const float*)s_MP4;
  float* mpw = (float*)s_MP4;

  // ---- fused precompute: wave-butterfly A^T B, 3 matrices per wave ----
  for (int m = wvid; m < 24; m += 8) {
    const int which = (m >= 12) ? 1 : 0;
    const int lh = which ? (m - 12) : m;
    float av0,av1,av2,av3,av4, bv0,bv1,bv2,bv3,bv4;
    if (which == 0) {
      const float* wq = Wq + lh*(DD*EDIM) + lane*5;
      const float* wk = Wk + lh*(DD*EDIM) + lane*5;
      av0=wq[0]; av1=wq[1]; av2=wq[2]; av3=wq[3]; av4=wq[4];
      bv0=wk[0]; bv1=wk[1]; bv2=wk[2]; bv3=wk[3]; bv4=wk[4];
    } else {
      const int l = lh >> 2, h = lh & 3;
      const float* wv_ = Wv + lh*(DD*EDIM) + lane*5;
      av0=wv_[0]; av1=wv_[1]; av2=wv_[2]; av3=wv_[3]; av4=wv_[4];
      const float* wo = Wo + l*EDIM*(NH*DD) + h*DD + lane;   // f stride 256
      bv0=wo[0]; bv1=wo[256]; bv2=wo[512]; bv3=wo[768]; bv4=wo[1024];
    }
    float pr[25];
    {
      const float av[5] = {av0,av1,av2,av3,av4};
      const float bv[5] = {bv0,bv1,bv2,bv3,bv4};
      #pragma unroll
      for (int e = 0; e < 5; ++e)
        #pragma unroll
        for (int f = 0; f < 5; ++f) pr[e*5+f] = av[e]*bv[f];
    }
    #pragma unroll
    for (int s = 1; s < 64; s <<= 1) {
      #pragma unroll
      for (int k = 0; k < 25; ++k) pr[k] += __shfl_xor(pr[k], s, 64);
    }
    if (lane == 0) {
      const float sc = which ? 1.f : 0.125f * 1.44269504088896340736f; // log2e fold
      #pragma unroll
      for (int e = 0; e < 5; ++e)
        #pragma unroll
        for (int f = 0; f < 5; ++f)
          mpw[which*960 + (lh*5 + e)*8 + f] = pr[e*5+f]*sc;
    }
  }
  for (int r = t; r < 150; r += BLK) {
    float v;
    if      (r <  75) v = Wf[r];
    else if (r <  90) v = bfv[r-75];
    else if (r < 105) v = g1[r-90];
    else if (r < 120) v = b1[r-105];
    else if (r < 135) v = g2[r-120];
    else              v = b2[r-135];
    s_cf[r] = v;
  }

  // ---- setup: mask + ballot-based compaction ----
  float k0=0.f, k1=0.f, k2=0.f, msk=0.f;
  if (t < NTOK) {
    k0 = x[b*300 + 3*t];
    k1 = x[b*300 + 3*t + 1];
    k2 = x[b*300 + 3*t + 2];
    msk = (k2 > 0.f) ? 1.f : 0.f;
  }
  unsigned long long bal = __ballot(t < NTOK && msk != 0.f);
  if (t == 0)  s_bal[0] = bal;
  if (t == 64) s_bal[1] = bal;
  __syncthreads();                          // also covers s_MP4/s_cf writes
  const unsigned long long bw0 = s_bal[0], bw1 = s_bal[1];
  // readfirstlane: nm (and all derived bounds) provably uniform
  const int nm = __builtin_amdgcn_readfirstlane(__popcll(bw0) + __popcll(bw1));
  if (t < NTOK) {
    unsigned long long lm = (lane == 0) ? 0ull : ((1ull << lane) - 1ull);
    int pre = (t < 64) ? __popcll(bw0 & lm) : (__popcll(bw0) + __popcll(bw1 & lm));
    if (msk != 0.f) {
      s_o4[pre] = make_float4(k0, k1, k2, __sinf((float)t));
      s_o1[pre] = __cosf((float)t);
      s_cidx[t] = pre;
    } else {
      s_cidx[t] = nm;
    }
  }
  if (t == 0) {
    s_o4[nm]   = make_float4(0.f,0.f,0.f,0.f); s_o1[nm]   = 0.f;  // rep token
    s_o4[nm+1] = make_float4(0.f,0.f,0.f,0.f); s_o1[nm+1] = 0.f;
  }
  __syncthreads();

  // ---- static task mapping: 1 row/thread, adaptive j-split ----
  const int rowsN = nm + 1;                 // rows incl. rep token
  const int natt  = NH * rowsN;             // threads per j-group (<=404)
  const int nsplit = (2*natt <= BLK) ? 2 : 1;   // nm<=63 -> 2 (typical)
  const bool task = (t < natt*nsplit);
  int h = 0, i0 = 0, jlo = 0, jhi = 0;
  bool rep0 = false, corr = false;
  if (task) {
    int g  = t / natt;
    int tt = t - g*natt;
    h = tt / rowsN; i0 = tt - h*rowsN;
    rep0 = (i0 == nm);
    corr = (g == 0);                        // rep-correction applied once
    int jmid = nm >> 1;
    if (nsplit == 2) { jlo = g ? jmid : 0; jhi = g ? nm : jmid; }
    else             { jlo = 0; jhi = nm; }
  }
  const int wg = task ? (t / natt) : 0;
  const float wext = (float)(NTOK - nm);

  for (int l = 0; l < NL; ++l) {
    if (task) {
      // a = o @ M_h for this thread's row
      const float* Mh = mpf + ((l*NH + h)*EDIM)*8;
      float4 oA = s_o4[i0];  float oA4 = s_o1[i0];
      float oa[5] = {oA.x, oA.y, oA.z, oA.w, oA4};
      float a0[5];
      #pragma unroll
      for (int f = 0; f < 5; ++f) a0[f] = 0.f;
      #pragma unroll
      for (int e = 0; e < 5; ++e) {
        float4 mr = *(const float4*)(Mh + e*8); float m4 = Mh[e*8+4];
        float va = oa[e];
        a0[0] += va*mr.x; a0[1] += va*mr.y; a0[2] += va*mr.z;
        a0[3] += va*mr.w; a0[4] += va*m4;
      }
      if (rep0) { a0[0]=0.f; a0[1]=0.f; a0[2]=0.f; a0[3]=0.f; a0[4]=0.f; } // exp2(0)=1

      // attention j-loop: LDS broadcast reads, 1-row body, native exp2
      float ls0=0.f;
      float w00=0.f,w01=0.f,w02=0.f,w03=0.f,w04=0.f;
      #pragma unroll 8
      for (int j = jlo; j < jhi; ++j) {
        float4 oj = s_o4[j]; float oe = s_o1[j];
        float s0 = (a0[0]*oj.x + a0[1]*oj.y) + ((a0[2]*oj.z + a0[3]*oj.w) + a0[4]*oe);
        float p0 = fexp2(s0);
        ls0 += p0;
        w00 += p0*oj.x; w01 += p0*oj.y; w02 += p0*oj.z; w03 += p0*oj.w; w04 += p0*oe;
      }
      // rep row: uniform 1/100 row also averages (100-nm) masked tokens,
      // each carrying the rep state itself (applied once, in group 0).
      if (rep0 && corr) {
        w00 += wext*oa[0]; w01 += wext*oa[1]; w02 += wext*oa[2];
        w03 += wext*oa[3]; w04 += wext*oa[4];
      }

      // P-apply in the DENSE phase: wp = w @ P_h (unnormalized; ls carried)
      const float* Ph = mpf + 960 + ((l*NH + h)*EDIM)*8;
      float wr0[5] = {w00,w01,w02,w03,w04};
      float c00=0.f,c01=0.f,c02=0.f,c03=0.f,c04=0.f;
      #pragma unroll
      for (int e = 0; e < 5; ++e) {
        float4 pr4 = *(const float4*)(Ph + e*8); float p4 = Ph[e*8+4];
        float va = wr0[e];
        c00 += va*pr4.x; c01 += va*pr4.y; c02 += va*pr4.z; c03 += va*pr4.w; c04 += va*p4;
      }
      s_w4[wg][h][i0] = make_float4(c00, c01, c02, c03);
      s_w2[wg][h][i0] = make_float2(c04, ls0);
    }
    __syncthreads();

    // ---- token pass: merge pre-applied head outputs, LN1, FFN, LN2 ----
    if (t <= nm) {
      int i = t;
      bool rep = (i == nm);
      float4 ov = s_o4[i]; float ov4 = s_o1[i];
      float y[5] = {ov.x, ov.y, ov.z, ov.w, ov4};
      #pragma unroll
      for (int hh = 0; hh < NH; ++hh) {
        float4 wa = s_w4[0][hh][i]; float2 wb = s_w2[0][hh][i];
        float c0 = wa.x, c1 = wa.y, c2 = wa.z, c3 = wa.w, c4 = wb.x;
        float ls = wb.y;
        if (nsplit == 2) {
          float4 wa2 = s_w4[1][hh][i]; float2 wb2 = s_w2[1][hh][i];
          c0 += wa2.x; c1 += wa2.y; c2 += wa2.z; c3 += wa2.w; c4 += wb2.x;
          ls += wb2.y;
        }
        float inv = rep ? 0.01f : frcp(ls);
        y[0] += c0*inv; y[1] += c1*inv; y[2] += c2*inv; y[3] += c3*inv; y[4] += c4*inv;
      }
      float mu = 0.2f*(y[0]+y[1]+y[2]+y[3]+y[4]);
      float var = 0.f;
      #pragma unroll
      for (int e = 0; e < 5; ++e) { float d = y[e]-mu; var += d*d; }
      float iv = frsq(var*0.2f + 1e-5f);
      float l1[5];
      #pragma unroll
      for (int e = 0; e < 5; ++e)
        l1[e] = (y[e]-mu)*iv*s_cf[90+l*5+e] + s_cf[105+l*5+e];
      float r2[5];
      #pragma unroll
      for (int e = 0; e < 5; ++e) {
        float acc = s_cf[75+l*5+e];
        #pragma unroll
        for (int f = 0; f < 5; ++f) acc += l1[f]*s_cf[l*25+e*5+f];
        acc = acc > 0.f ? acc : 0.f;
        r2[e] = acc + l1[e];
      }
      float mu2 = 0.2f*(r2[0]+r2[1]+r2[2]+r2[3]+r2[4]);
      float var2 = 0.f;
      #pragma unroll
      for (int e = 0; e < 5; ++e) { float d = r2[e]-mu2; var2 += d*d; }
      float iv2 = frsq(var2*0.2f + 1e-5f);
      float no0 = (r2[0]-mu2)*iv2*s_cf[120+l*5+0] + s_cf[135+l*5+0];
      float no1 = (r2[1]-mu2)*iv2*s_cf[120+l*5+1] + s_cf[135+l*5+1];
      float no2 = (r2[2]-mu2)*iv2*s_cf[120+l*5+2] + s_cf[135+l*5+2];
      float no3 = (r2[3]-mu2)*iv2*s_cf[120+l*5+3] + s_cf[135+l*5+3];
      float no4 = (r2[4]-mu2)*iv2*s_cf[120+l*5+4] + s_cf[135+l*5+4];
      s_o4[i] = make_float4(no0, no1, no2, no3);
      s_o1[i] = no4;
    }
    __syncthreads();
  }

  // ---- expand compacted state back to [N, E] ----
  for (int r = t; r < NTOK*EDIM; r += BLK) {
    int i = r / EDIM;
    int e = r - i*EDIM;
    int c = s_cidx[i];
    float v = (e < 4) ? ((const float*)&s_o4[c])[e] : s_o1[c];
    out[b*(NTOK*EDIM) + r] = v;
  }
}

extern "C" void kernel_launch(void* const* d_in, const int* in_sizes, int n_in,
                              void* d_out, int out_size, void* d_ws, size_t ws_size,
                              hipStream_t stream) {
  const float* x  = (const float*)d_in[0];
  const float* Wq = (const float*)d_in[1];
  const float* Wk = (const float*)d_in[2];
  const float* Wv = (const float*)d_in[3];
  const float* Wo = (const float*)d_in[4];
  const float* Wf = (const float*)d_in[5];
  const float* bf = (const float*)d_in[6];
  const float* g1 = (const float*)d_in[7];
  const float* b1 = (const float*)d_in[8];
  const float* g2 = (const float*)d_in[9];
  const float* b2 = (const float*)d_in[10];
  float* outp = (float*)d_out;

  encoder_kernel<<<1024, BLK, 0, stream>>>(x, Wq, Wk, Wv, Wo,
                                           Wf, bf, g1, b1, g2, b2, outp);
}

// Round 12
// 115.160 us; speedup vs baseline: 1.2405x; 1.2405x over previous
//
#include <hip/hip_runtime.h>
#include <math.h>

#define NTOK 100
#define EDIM 5
#define NH   4
#define NL   3
#define DD   64
#define BLK  512

// single-instruction transcendentals (1-ulp class; tolerance is 2^-7;
// HW-validated rounds 3-11)
__device__ __forceinline__ float fexp2(float x){ float r; asm("v_exp_f32 %0, %1" : "=v"(r) : "v"(x)); return r; }
__device__ __forceinline__ float frcp (float x){ float r; asm("v_rcp_f32 %0, %1" : "=v"(r) : "v"(x)); return r; }
__device__ __forceinline__ float frsq (float x){ float r; asm("v_rsq_f32 %0, %1" : "=v"(r) : "v"(x)); return r; }

// ---------------------------------------------------------------------------
// Kernel 1: fold per-head projections into 5x5 matrices (SEPARATE kernel --
// rounds 10/11 proved per-block fused precompute costs 23-38 us vs ~7.7 us
// for the extra launch; two-kernel is the proven optimum).
//   M[l][h] = (1/8)*log2(e) * Wq^T Wk    (softmax uses native v_exp_f32)
//   P[l][h] = Wv^T Wo_h^T
// ws layout: float [2][NL][NH][EDIM][8]
// ---------------------------------------------------------------------------
__global__ void precompute_mp(const float* __restrict__ Wq,
                              const float* __restrict__ Wk,
                              const float* __restrict__ Wv,
                              const float* __restrict__ Wo,
                              float* __restrict__ mp) {
  const int blk = blockIdx.x;            // 24 = which(2) * l(3) * h(4)
  const int which = blk / 12;
  const int rem = blk % 12;
  const int l = rem / 4, h = rem % 4;
  const int t = threadIdx.x;             // 64 threads

  __shared__ float A[320];               // [d*5+e]
  __shared__ float Bsh[320];             // which0: [d*5+f] ; which1: [f*64+d]

  const float* wa = (which ? Wv : Wq) + (l*NH + h)*DD*EDIM;
  for (int r = t; r < 320; r += 64) A[r] = wa[r];
  if (which == 0) {
    const float* wk = Wk + (l*NH + h)*DD*EDIM;
    for (int r = t; r < 320; r += 64) Bsh[r] = wk[r];
  } else {
    for (int r = t; r < 320; r += 64) {
      int f = r >> 6, d = r & 63;
      Bsh[r] = Wo[(l*EDIM + f)*(NH*DD) + h*DD + d];
    }
  }
  __syncthreads();
  if (t < 25) {
    int e = t / 5, f = t % 5;
    float acc = 0.f;
    if (which == 0) {
      #pragma unroll 8
      for (int d = 0; d < DD; ++d) acc += A[d*5+e] * Bsh[d*5+f];
      acc *= 0.125f * 1.44269504088896340736f;   // fold log2(e) for exp2
    } else {
      #pragma unroll 8
      for (int d = 0; d < DD; ++d) acc += A[d*5+e] * Bsh[f*64+d];
    }
    mp[which*960 + ((l*NH + h)*EDIM + e)*8 + f] = acc;
  }
}

// ---------------------------------------------------------------------------
// Kernel 2 (round 12): r9's proven base, with BOTH phases dense:
//   * NO j-split: thread (h,i) owns the COMPLETE softmax row (full j-range)
//     -> no duplicated M/P/a setup, no 2-group ls/wp merge.
//   * attention thread normalizes + P-applies -> exchange is 5 floats/row.
//   * token pass is DENSE-REDUNDANT: all 404 (h,i) threads compute row i's
//     residual+LN1+FFN+LN2 identically (bit-identical FP) and 4-way
//     same-value-write o[i].  Benign because each thread cached its own
//     o[i] (oa[]) in registers during attention -- token pass reads only
//     w[*][i] + registers, never o.
//   * 2 barriers/layer remain (both true deps: w-visibility, o-visibility)
//     but no phase runs below 404/512 threads (r9's token pass: 51/512).
// Lean math from r3-r9 retained: log2e in M, rep row via a=0, native
// v_exp/v_rcp/v_rsq, readfirstlane(nm), LN/FFN constants in LDS.
// ---------------------------------------------------------------------------
__global__ __launch_bounds__(BLK, 4) void encoder_kernel(
    const float* __restrict__ x,
    const float* __restrict__ mp,
    const float* __restrict__ Wf,
    const float* __restrict__ bfv,
    const float* __restrict__ g1,
    const float* __restrict__ b1,
    const float* __restrict__ g2,
    const float* __restrict__ b2,
    float* __restrict__ out)
{
  const int b = blockIdx.x, t = threadIdx.x;

  __shared__ float4 s_MP4[480];             // 7680 B: M then P
  __shared__ float4 s_o4[NTOK+2];           // token state [0..3]
  __shared__ float  s_o1[NTOK+2];           // token state [4]
  __shared__ float4 s_w4[NH][NTOK+2];       // wp[0..3] per (h,i)  (normalized)
  __shared__ float  s_w1[NH][NTOK+2];       // wp[4]
  __shared__ float  s_cf[152];              // Wf | bf | g1 | b1 | g2 | b2
  __shared__ int    s_cidx[NTOK];
  __shared__ unsigned long long s_bal[2];

  const float* mpf = (const float*)s_MP4;

  for (int r = t; r < 480; r += BLK) s_MP4[r] = ((const float4*)mp)[r];
  for (int r = t; r < 150; r += BLK) {
    float v;
    if      (r <  75) v = Wf[r];
    else if (r <  90) v = bfv[r-75];
    else if (r < 105) v = g1[r-90];
    else if (r < 120) v = b1[r-105];
    else if (r < 135) v = g2[r-120];
    else              v = b2[r-135];
    s_cf[r] = v;
  }

  // ---- setup: mask + ballot-based compaction ----
  float k0=0.f, k1=0.f, k2=0.f, msk=0.f;
  if (t < NTOK) {
    k0 = x[b*300 + 3*t];
    k1 = x[b*300 + 3*t + 1];
    k2 = x[b*300 + 3*t + 2];
    msk = (k2 > 0.f) ? 1.f : 0.f;
  }
  unsigned long long bal = __ballot(t < NTOK && msk != 0.f);
  if (t == 0)  s_bal[0] = bal;
  if (t == 64) s_bal[1] = bal;
  __syncthreads();
  const unsigned long long bw0 = s_bal[0], bw1 = s_bal[1];
  // readfirstlane: nm (and all derived bounds) provably uniform
  const int nm = __builtin_amdgcn_readfirstlane(__popcll(bw0) + __popcll(bw1));
  if (t < NTOK) {
    int lane = t & 63;
    unsigned long long lm = (lane == 0) ? 0ull : ((1ull << lane) - 1ull);
    int pre = (t < 64) ? __popcll(bw0 & lm) : (__popcll(bw0) + __popcll(bw1 & lm));
    if (msk != 0.f) {
      s_o4[pre] = make_float4(k0, k1, k2, __sinf((float)t));
      s_o1[pre] = __cosf((float)t);
      s_cidx[t] = pre;
    } else {
      s_cidx[t] = nm;
    }
  }
  if (t == 0) {
    s_o4[nm]   = make_float4(0.f,0.f,0.f,0.f); s_o1[nm]   = 0.f;  // rep token
    s_o4[nm+1] = make_float4(0.f,0.f,0.f,0.f); s_o1[nm+1] = 0.f;
  }
  __syncthreads();

  // ---- static task mapping: thread (h,i) owns one full softmax row ----
  const int rowsN = nm + 1;                 // rows incl. rep token
  const int natt  = NH * rowsN;             // active threads (<=404)
  const bool task = (t < natt);
  int h = 0, i0 = 0;
  bool rep0 = false;
  if (task) {
    h = t / rowsN; i0 = t - h*rowsN;
    rep0 = (i0 == nm);
  }
  const float wext = (float)(NTOK - nm);

  for (int l = 0; l < NL; ++l) {
    float oa[5];                            // own row, cached for token pass
    if (task) {
      // a = o @ M_h
      const float* Mh = mpf + ((l*NH + h)*EDIM)*8;
      float4 oA = s_o4[i0];  float oA4 = s_o1[i0];
      oa[0]=oA.x; oa[1]=oA.y; oa[2]=oA.z; oa[3]=oA.w; oa[4]=oA4;
      float a0[5];
      #pragma unroll
      for (int f = 0; f < 5; ++f) a0[f] = 0.f;
      #pragma unroll
      for (int e = 0; e < 5; ++e) {
        float4 mr = *(const float4*)(Mh + e*8); float m4 = Mh[e*8+4];
        float va = oa[e];
        a0[0] += va*mr.x; a0[1] += va*mr.y; a0[2] += va*mr.z;
        a0[3] += va*mr.w; a0[4] += va*m4;
      }
      if (rep0) { a0[0]=0.f; a0[1]=0.f; a0[2]=0.f; a0[3]=0.f; a0[4]=0.f; } // exp2(0)=1

      // attention j-loop: FULL row, LDS broadcast reads, native exp2
      float ls0=0.f;
      float w00=0.f,w01=0.f,w02=0.f,w03=0.f,w04=0.f;
      #pragma unroll 8
      for (int j = 0; j < nm; ++j) {
        float4 oj = s_o4[j]; float oe = s_o1[j];
        float s0 = (a0[0]*oj.x + a0[1]*oj.y) + ((a0[2]*oj.z + a0[3]*oj.w) + a0[4]*oe);
        float p0 = fexp2(s0);
        ls0 += p0;
        w00 += p0*oj.x; w01 += p0*oj.y; w02 += p0*oj.z; w03 += p0*oj.w; w04 += p0*oe;
      }
      // rep row: uniform 1/100 row also averages (100-nm) masked tokens,
      // each carrying the rep state itself.
      if (rep0) {
        w00 += wext*oa[0]; w01 += wext*oa[1]; w02 += wext*oa[2];
        w03 += wext*oa[3]; w04 += wext*oa[4];
      }

      // normalize (this thread owns the full row) + P-apply
      float inv = rep0 ? 0.01f : frcp(ls0);
      const float* Ph = mpf + 960 + ((l*NH + h)*EDIM)*8;
      float wr0[5] = {w00*inv, w01*inv, w02*inv, w03*inv, w04*inv};
      float c00=0.f,c01=0.f,c02=0.f,c03=0.f,c04=0.f;
      #pragma unroll
      for (int e = 0; e < 5; ++e) {
        float4 pr = *(const float4*)(Ph + e*8); float p4 = Ph[e*8+4];
        float va = wr0[e];
        c00 += va*pr.x; c01 += va*pr.y; c02 += va*pr.z; c03 += va*pr.w; c04 += va*p4;
      }
      s_w4[h][i0] = make_float4(c00, c01, c02, c03);
      s_w1[h][i0] = c04;
    }
    __syncthreads();   // barrier 1: wp visible

    // ---- token pass: DENSE-REDUNDANT (all 4 h-threads of row i compute
    // identical results from identical inputs; 4-way same-value write) ----
    if (task) {
      float y[5] = {oa[0], oa[1], oa[2], oa[3], oa[4]};   // o from registers
      #pragma unroll
      for (int hh = 0; hh < NH; ++hh) {
        float4 wa = s_w4[hh][i0];
        y[0] += wa.x; y[1] += wa.y; y[2] += wa.z; y[3] += wa.w;
        y[4] += s_w1[hh][i0];
      }
      float mu = 0.2f*(y[0]+y[1]+y[2]+y[3]+y[4]);
      float var = 0.f;
      #pragma unroll
      for (int e = 0; e < 5; ++e) { float d = y[e]-mu; var += d*d; }
      float iv = frsq(var*0.2f + 1e-5f);
      float l1[5];
      #pragma unroll
      for (int e = 0; e < 5; ++e)
        l1[e] = (y[e]-mu)*iv*s_cf[90+l*5+e] + s_cf[105+l*5+e];
      float r2[5];
      #pragma unroll
      for (int e = 0; e < 5; ++e) {
        float acc = s_cf[75+l*5+e];
        #pragma unroll
        for (int f = 0; f < 5; ++f) acc += l1[f]*s_cf[l*25+e*5+f];
        acc = acc > 0.f ? acc : 0.f;
        r2[e] = acc + l1[e];
      }
      float mu2 = 0.2f*(r2[0]+r2[1]+r2[2]+r2[3]+r2[4]);
      float var2 = 0.f;
      #pragma unroll
      for (int e = 0; e < 5; ++e) { float d = r2[e]-mu2; var2 += d*d; }
      float iv2 = frsq(var2*0.2f + 1e-5f);
      float no0 = (r2[0]-mu2)*iv2*s_cf[120+l*5+0] + s_cf[135+l*5+0];
      float no1 = (r2[1]-mu2)*iv2*s_cf[120+l*5+1] + s_cf[135+l*5+1];
      float no2 = (r2[2]-mu2)*iv2*s_cf[120+l*5+2] + s_cf[135+l*5+2];
      float no3 = (r2[3]-mu2)*iv2*s_cf[120+l*5+3] + s_cf[135+l*5+3];
      float no4 = (r2[4]-mu2)*iv2*s_cf[120+l*5+4] + s_cf[135+l*5+4];
      s_o4[i0] = make_float4(no0, no1, no2, no3);   // 4-way same-value write
      s_o1[i0] = no4;
    }
    __syncthreads();   // barrier 2: o visible for next layer
  }

  // ---- expand compacted state back to [N, E] ----
  for (int r = t; r < NTOK*EDIM; r += BLK) {
    int i = r / EDIM;
    int e = r - i*EDIM;
    int c = s_cidx[i];
    float v = (e < 4) ? ((const float*)&s_o4[c])[e] : s_o1[c];
    out[b*(NTOK*EDIM) + r] = v;
  }
}

extern "C" void kernel_launch(void* const* d_in, const int* in_sizes, int n_in,
                              void* d_out, int out_size, void* d_ws, size_t ws_size,
                              hipStream_t stream) {
  const float* x  = (const float*)d_in[0];
  const float* Wq = (const float*)d_in[1];
  const float* Wk = (const float*)d_in[2];
  const float* Wv = (const float*)d_in[3];
  const float* Wo = (const float*)d_in[4];
  const float* Wf = (const float*)d_in[5];
  const float* bf = (const float*)d_in[6];
  const float* g1 = (const float*)d_in[7];
  const float* b1 = (const float*)d_in[8];
  const float* g2 = (const float*)d_in[9];
  const float* b2 = (const float*)d_in[10];
  float* outp = (float*)d_out;
  float* mp   = (float*)d_ws;   // 1920 floats

  precompute_mp<<<24, 64, 0, stream>>>(Wq, Wk, Wv, Wo, mp);
  encoder_kernel<<<1024, BLK, 0, stream>>>(x, mp, Wf, bf, g1, b1, g2, b2, outp);
}